// Round 1
// baseline (458.393 us; speedup 1.0000x reference)
//
#include <hip/hip_runtime.h>
#include <cstdint>
#include <cstddef>

typedef unsigned short ushort_t;
typedef __bf16 bf16x8 __attribute__((ext_vector_type(8)));
typedef float f32x4 __attribute__((ext_vector_type(4)));

__device__ __forceinline__ ushort_t f2bf(float x) {
    union { float f; uint32_t u; } v; v.f = x;
    return (ushort_t)((v.u + 0x7FFFu + ((v.u >> 16) & 1u)) >> 16);
}

// async global->LDS, 16B per lane. LDS dest = wave-uniform base + lane*16.
__device__ __forceinline__ void gld_lds16(const void* g, void* l) {
    __builtin_amdgcn_global_load_lds(
        (const __attribute__((address_space(1))) uint32_t*)g,
        (__attribute__((address_space(3))) uint32_t*)l,
        16, 0, 0);
}

// ---------------------------------------------------------------------------
// Kernel 1: W [H,V] fp32  ->  Wt [V,H] bf16   (B^T layout for the GEMM)
// 64x64 tiles through LDS; reads and writes both coalesced.
// ---------------------------------------------------------------------------
__global__ __launch_bounds__(256) void transpose_convert(
    const float* __restrict__ Wm, ushort_t* __restrict__ Wt, int H, int V)
{
    __shared__ ushort_t tile[64][65];  // +1 pad to spread bank access
    const int v0 = blockIdx.x * 64;
    const int k0 = blockIdx.y * 64;
    const int tx = threadIdx.x & 63;
    const int ty = threadIdx.x >> 6;   // 0..3

    #pragma unroll
    for (int i = ty; i < 64; i += 4)
        tile[i][tx] = f2bf(Wm[(size_t)(k0 + i) * V + v0 + tx]);
    __syncthreads();
    #pragma unroll
    for (int i = ty; i < 64; i += 4)
        Wt[(size_t)(v0 + i) * H + k0 + tx] = tile[tx][i];
}

// ---------------------------------------------------------------------------
// Kernel 2: segment mean. One block per (b, w). segment_ids sorted per row ->
// binary search [lo,hi), mean over tokens, write bf16 merged [B*W, H].
// Empty words -> 0 (matches reference zero-padding).
// ---------------------------------------------------------------------------
__global__ __launch_bounds__(256) void seg_mean(
    const float* __restrict__ enc,   // [B, S, H]
    const int*   __restrict__ seg,   // [B, S]
    ushort_t*    __restrict__ merged,// [B*W, H] bf16
    int S, int H, int W)
{
    const int bw = blockIdx.x;
    const int b  = bw / W;
    const int w  = bw - b * W;
    const int* srow = seg + (size_t)b * S;

    // lower_bound(w)
    int l = 0, r = S;
    while (l < r) { int m = (l + r) >> 1; if (srow[m] < w) l = m + 1; else r = m; }
    const int lo = l;
    // lower_bound(w+1), continuing from lo
    r = S;
    while (l < r) { int m = (l + r) >> 1; if (srow[m] < w + 1) l = m + 1; else r = m; }
    const int hi = l;

    const int cnt = hi - lo;
    const float scale = (cnt > 0) ? (1.0f / (float)cnt) : 0.0f;
    const float* erow = enc + (size_t)b * S * H;
    ushort_t* orow = merged + (size_t)bw * H;

    for (int h = threadIdx.x; h < H; h += 256) {
        float s = 0.0f;
        for (int t = lo; t < hi; ++t) s += erow[(size_t)t * H + h];
        orow[h] = f2bf(s * scale);
    }
}

// ---------------------------------------------------------------------------
// Kernel 3: C[M,N] = A[M,K] * Bt[N,K]^T + bias[N]   (bf16 in, fp32 out)
// 128x128 block tile, BK=32, 4 waves in 2x2 (each 64x64),
// mfma_f32_16x16x32_bf16, global_load_lds width-16 staging (m97 structure).
// M=8192, N=8192, K=768 all divide tile sizes exactly -> no bounds checks.
// ---------------------------------------------------------------------------
__global__ __launch_bounds__(256) void gemm_bt(
    const ushort_t* __restrict__ A,   // [M,K] bf16 (merged)
    const ushort_t* __restrict__ Bt,  // [N,K] bf16 (Wt)
    const float*    __restrict__ bias,// [N]
    float*          __restrict__ C,   // [M,N]
    int M, int N, int K)
{
    __shared__ ushort_t As[128 * 32];
    __shared__ ushort_t Bs[128 * 32];

    const int tid  = threadIdx.x;
    const int wave = tid >> 6;
    const int lane = tid & 63;
    const int wm   = wave >> 1;      // wave row (0..1)
    const int wn   = wave & 1;       // wave col (0..1)
    const int r15  = lane & 15;
    const int quad = lane >> 4;

    const int m0 = blockIdx.y * 128;
    const int n0 = blockIdx.x * 128;

    // staging: thread t covers tile row t/4 (and t/4+64), cols (t%4)*8..+8
    const int srow = tid >> 2;          // 0..63
    const int scol = (tid & 3) * 8;

    const ushort_t* Ag = A  + (size_t)(m0 + srow) * K + scol;
    const ushort_t* Bg = Bt + (size_t)(n0 + srow) * K + scol;
    ushort_t* AsW = As + wave * 512;   // wave-uniform LDS base (elements)
    ushort_t* BsW = Bs + wave * 512;

    f32x4 acc[4][4] = {};

    const ushort_t* a_lds = As + (wm * 64 + r15) * 32 + quad * 8;
    const ushort_t* b_lds = Bs + (wn * 64 + r15) * 32 + quad * 8;

    for (int kt = 0; kt < K; kt += 32) {
        gld_lds16(Ag + kt,                   AsW);
        gld_lds16(Ag + (size_t)64 * K + kt,  AsW + 2048);
        gld_lds16(Bg + kt,                   BsW);
        gld_lds16(Bg + (size_t)64 * K + kt,  BsW + 2048);
        __syncthreads();   // drains vmcnt before barrier (compiler-inserted)

        bf16x8 af[4], bf[4];
        #pragma unroll
        for (int i = 0; i < 4; ++i) {
            af[i] = *(const bf16x8*)(a_lds + i * 16 * 32);
            bf[i] = *(const bf16x8*)(b_lds + i * 16 * 32);
        }
        #pragma unroll
        for (int i = 0; i < 4; ++i)
            #pragma unroll
            for (int j = 0; j < 4; ++j)
                acc[i][j] = __builtin_amdgcn_mfma_f32_16x16x32_bf16(
                                af[i], bf[j], acc[i][j], 0, 0, 0);
        __syncthreads();
    }

    // epilogue: C/D layout col = lane&15, row = quad*4 + reg
    const int crow = m0 + wm * 64 + quad * 4;
    const int ccol = n0 + wn * 64 + r15;
    #pragma unroll
    for (int j = 0; j < 4; ++j) {
        const float bv = bias[ccol + j * 16];
        #pragma unroll
        for (int i = 0; i < 4; ++i) {
            float* cp = C + (size_t)(crow + i * 16) * N + (ccol + j * 16);
            #pragma unroll
            for (int r = 0; r < 4; ++r)
                cp[(size_t)r * N] = acc[i][j][r] + bv;
        }
    }
}

// ---------------------------------------------------------------------------
extern "C" void kernel_launch(void* const* d_in, const int* in_sizes, int n_in,
                              void* d_out, int out_size, void* d_ws, size_t ws_size,
                              hipStream_t stream) {
    const float* enc  = (const float*)d_in[0];  // [B,S,H] fp32
    const int*   seg  = (const int*)d_in[1];    // [B,S]
    const float* Wm   = (const float*)d_in[2];  // [H,V] fp32
    const float* bias = (const float*)d_in[3];  // [V]
    // d_in[4] = num_words (scalar on device); fixed at 256 by the reference.

    const int B = 32, S = 512, H = 768, V = 8192, WMAX = 256;
    const int M = B * WMAX;  // 8192

    ushort_t* Wt     = (ushort_t*)d_ws;               // [V,H] bf16 : 12.58 MB
    ushort_t* merged = Wt + (size_t)V * H;            // [M,H] bf16 : 12.58 MB
    float*    out    = (float*)d_out;                 // [M,V] fp32

    hipLaunchKernelGGL(transpose_convert, dim3(V / 64, H / 64), dim3(256), 0, stream,
                       Wm, Wt, H, V);
    hipLaunchKernelGGL(seg_mean, dim3(M), dim3(256), 0, stream,
                       enc, seg, merged, S, H, WMAX);
    hipLaunchKernelGGL(gemm_bt, dim3(V / 128, M / 128), dim3(256), 0, stream,
                       merged, Wt, bias, out, M, V, H);
}

// Round 2
// 449.821 us; speedup vs baseline: 1.0191x; 1.0191x over previous
//
#include <hip/hip_runtime.h>
#include <cstdint>
#include <cstddef>

typedef unsigned short ushort_t;
typedef __bf16 bf16x8 __attribute__((ext_vector_type(8)));
typedef float f32x4 __attribute__((ext_vector_type(4)));
typedef float f32x4v __attribute__((ext_vector_type(4)));
typedef unsigned short u16x4 __attribute__((ext_vector_type(4)));
typedef unsigned short u16x8 __attribute__((ext_vector_type(8)));

__device__ __forceinline__ ushort_t f2bf(float x) {
    union { float f; uint32_t u; } v; v.f = x;
    return (ushort_t)((v.u + 0x7FFFu + ((v.u >> 16) & 1u)) >> 16);
}

// async global->LDS, 16B per lane. LDS dest = wave-uniform base + lane*16.
__device__ __forceinline__ void gld_lds16(const void* g, void* l) {
    __builtin_amdgcn_global_load_lds(
        (const __attribute__((address_space(1))) uint32_t*)g,
        (__attribute__((address_space(3))) uint32_t*)l,
        16, 0, 0);
}

// ---------------------------------------------------------------------------
// Kernel 1: W [H,V] fp32 -> Wt [V,H] bf16 (B^T layout for the GEMM).
// 64x64 tiles; float4 global reads, ushort8 (16B) LDS reads + global stores.
// ---------------------------------------------------------------------------
__global__ __launch_bounds__(256) void transpose_convert(
    const float* __restrict__ Wm, ushort_t* __restrict__ Wt, int H, int V)
{
    __shared__ ushort_t tile[64][72];  // [v][k], row = 144 B (16B-aligned, bank-spread)
    const int v0 = blockIdx.x * 64;
    const int k0 = blockIdx.y * 64;
    const int tid = threadIdx.x;

    // Phase 1: 4 passes x (256 threads x float4) covers 64x64 fp32
    #pragma unroll
    for (int p = 0; p < 4; ++p) {
        const int krow = p * 16 + (tid >> 4);     // 0..63
        const int vcol = (tid & 15) * 4;          // 0..60
        const f32x4v w = *(const f32x4v*)&Wm[(size_t)(k0 + krow) * V + v0 + vcol];
        tile[vcol + 0][krow] = f2bf(w.x);
        tile[vcol + 1][krow] = f2bf(w.y);
        tile[vcol + 2][krow] = f2bf(w.z);
        tile[vcol + 3][krow] = f2bf(w.w);
    }
    __syncthreads();
    // Phase 2: 2 passes x (256 threads x ushort8=16B) covers 64x64 bf16
    #pragma unroll
    for (int p = 0; p < 2; ++p) {
        const int idx = p * 256 + tid;            // 0..511
        const int v = idx >> 3;                   // 0..63
        const int c = (idx & 7) * 8;              // 0..56
        const u16x8 val = *(const u16x8*)&tile[v][c];
        *(u16x8*)&Wt[(size_t)(v0 + v) * H + k0 + c] = val;
    }
}

// ---------------------------------------------------------------------------
// Kernel 2: segment mean, one WAVE per (b,w). Sorted ids -> binary search
// [lo,hi); float4 loads (64 lanes x 16B = 1KB coalesced); ushort4 stores.
// ---------------------------------------------------------------------------
__global__ __launch_bounds__(256) void seg_mean(
    const float* __restrict__ enc,   // [B, S, H]
    const int*   __restrict__ seg,   // [B, S]
    ushort_t*    __restrict__ merged,// [B*W, H] bf16
    int S, int H, int W)
{
    const int wave = threadIdx.x >> 6;
    const int lane = threadIdx.x & 63;
    const int bw = blockIdx.x * 4 + wave;          // word index in [0, B*W)
    const int b  = bw >> 8;                        // W = 256
    const int w  = bw & 255;
    const int* srow = seg + (size_t)b * S;

    // lower_bound(w) then lower_bound(w+1); uniform across lanes (broadcast loads)
    int l = 0, r = S;
    while (l < r) { int m = (l + r) >> 1; if (srow[m] < w) l = m + 1; else r = m; }
    const int lo = l;
    r = S;
    while (l < r) { int m = (l + r) >> 1; if (srow[m] < w + 1) l = m + 1; else r = m; }
    const int hi = l;

    const int cnt = hi - lo;
    const float scale = (cnt > 0) ? (1.0f / (float)cnt) : 0.0f;
    const float* erow = enc + (size_t)b * S * H;
    ushort_t* orow = merged + (size_t)bw * H;

    // H=768 floats = 3 chunks of (64 lanes x float4)
    #pragma unroll
    for (int c = 0; c < 3; ++c) {
        const int col = c * 256 + lane * 4;
        f32x4v s = {0.f, 0.f, 0.f, 0.f};
        for (int t = lo; t < hi; ++t) {
            const f32x4v v = *(const f32x4v*)&erow[(size_t)t * H + col];
            s.x += v.x; s.y += v.y; s.z += v.z; s.w += v.w;
        }
        u16x4 o;
        o.x = f2bf(s.x * scale); o.y = f2bf(s.y * scale);
        o.z = f2bf(s.z * scale); o.w = f2bf(s.w * scale);
        *(u16x4*)&orow[col] = o;
    }
}

// ---------------------------------------------------------------------------
// Kernel 3: C[M,N] = A[M,K] * Bt[N,K]^T + bias[N]  (bf16 in, fp32 out)
// 128x128 block tile, BK=64 (two 32-wide LDS buffer pairs per barrier),
// 4 waves in 2x2 (each 64x64), mfma_f32_16x16x32_bf16,
// global_load_lds width-16 staging. Barrier count halved vs BK=32.
// ---------------------------------------------------------------------------
__global__ __launch_bounds__(256) void gemm_bt(
    const ushort_t* __restrict__ A,   // [M,K] bf16 (merged)
    const ushort_t* __restrict__ Bt,  // [N,K] bf16 (Wt)
    const float*    __restrict__ bias,// [N]
    float*          __restrict__ C,   // [M,N]
    int M, int N, int K)
{
    __shared__ ushort_t As[2][128 * 32];
    __shared__ ushort_t Bs[2][128 * 32];

    const int tid  = threadIdx.x;
    const int wave = tid >> 6;
    const int lane = tid & 63;
    const int wm   = wave >> 1;      // wave row (0..1)
    const int wn   = wave & 1;       // wave col (0..1)
    const int r15  = lane & 15;
    const int quad = lane >> 4;

    const int m0 = blockIdx.y * 128;
    const int n0 = blockIdx.x * 128;

    // staging: thread t covers tile row t/4 (and t/4+64), cols (t%4)*8..+8
    const int srow = tid >> 2;          // 0..63
    const int scol = (tid & 3) * 8;

    const ushort_t* Ag = A  + (size_t)(m0 + srow) * K + scol;
    const ushort_t* Bg = Bt + (size_t)(n0 + srow) * K + scol;
    const int wofs = wave * 512;        // wave-uniform LDS base (elements)

    f32x4 acc[4][4] = {};

    const int a_fo = (wm * 64 + r15) * 32 + quad * 8;  // fragment offset in a 128x32 buf
    const int b_fo = (wn * 64 + r15) * 32 + quad * 8;

    for (int kt = 0; kt < K; kt += 64) {
        // stage both 32-wide halves, then ONE barrier
        gld_lds16(Ag + kt,                        &As[0][wofs]);
        gld_lds16(Ag + (size_t)64 * K + kt,       &As[0][wofs + 2048]);
        gld_lds16(Bg + kt,                        &Bs[0][wofs]);
        gld_lds16(Bg + (size_t)64 * K + kt,       &Bs[0][wofs + 2048]);
        gld_lds16(Ag + kt + 32,                   &As[1][wofs]);
        gld_lds16(Ag + (size_t)64 * K + kt + 32,  &As[1][wofs + 2048]);
        gld_lds16(Bg + kt + 32,                   &Bs[1][wofs]);
        gld_lds16(Bg + (size_t)64 * K + kt + 32,  &Bs[1][wofs + 2048]);
        __syncthreads();

        #pragma unroll
        for (int h = 0; h < 2; ++h) {
            bf16x8 af[4], bf[4];
            #pragma unroll
            for (int i = 0; i < 4; ++i) {
                af[i] = *(const bf16x8*)(&As[h][a_fo + i * 16 * 32]);
                bf[i] = *(const bf16x8*)(&Bs[h][b_fo + i * 16 * 32]);
            }
            #pragma unroll
            for (int i = 0; i < 4; ++i)
                #pragma unroll
                for (int j = 0; j < 4; ++j)
                    acc[i][j] = __builtin_amdgcn_mfma_f32_16x16x32_bf16(
                                    af[i], bf[j], acc[i][j], 0, 0, 0);
        }
        __syncthreads();
    }

    // epilogue: C/D layout col = lane&15, row = quad*4 + reg
    const int crow = m0 + wm * 64 + quad * 4;
    const int ccol = n0 + wn * 64 + r15;
    #pragma unroll
    for (int j = 0; j < 4; ++j) {
        const float bv = bias[ccol + j * 16];
        #pragma unroll
        for (int i = 0; i < 4; ++i) {
            float* cp = C + (size_t)(crow + i * 16) * N + (ccol + j * 16);
            #pragma unroll
            for (int r = 0; r < 4; ++r)
                cp[(size_t)r * N] = acc[i][j][r] + bv;
        }
    }
}

// ---------------------------------------------------------------------------
extern "C" void kernel_launch(void* const* d_in, const int* in_sizes, int n_in,
                              void* d_out, int out_size, void* d_ws, size_t ws_size,
                              hipStream_t stream) {
    const float* enc  = (const float*)d_in[0];  // [B,S,H] fp32
    const int*   seg  = (const int*)d_in[1];    // [B,S]
    const float* Wm   = (const float*)d_in[2];  // [H,V] fp32
    const float* bias = (const float*)d_in[3];  // [V]

    const int B = 32, S = 512, H = 768, V = 8192, WMAX = 256;
    const int M = B * WMAX;  // 8192

    ushort_t* Wt     = (ushort_t*)d_ws;               // [V,H] bf16 : 12.58 MB
    ushort_t* merged = Wt + (size_t)V * H;            // [M,H] bf16 : 12.58 MB
    float*    out    = (float*)d_out;                 // [M,V] fp32

    hipLaunchKernelGGL(transpose_convert, dim3(V / 64, H / 64), dim3(256), 0, stream,
                       Wm, Wt, H, V);
    hipLaunchKernelGGL(seg_mean, dim3(M / 4), dim3(256), 0, stream,
                       enc, seg, merged, S, H, WMAX);
    hipLaunchKernelGGL(gemm_bt, dim3(V / 128, M / 128), dim3(256), 0, stream,
                       merged, Wt, bias, out, M, V, H);
}